// Round 1
// baseline (1196.990 us; speedup 1.0000x reference)
//
#include <hip/hip_runtime.h>
#include <hip/hip_bf16.h>
#include <stdint.h>

// Problem constants (fixed by the reference)
#define TAUF 0.1f
#define MIN_SCOREF 0.5f
#define KTOP 256
#define BASE 130
#define BASE2 16900
#define TABLE_N 4394000   // 260*130*130 covers all neighbor keys
#define NEGF (-1e30f)
#define CAP2 3072
#define NS 4096

// ---------------------------------------------------------------- build table
__global__ void k_build(const int* __restrict__ coords, int* __restrict__ table,
                        int* __restrict__ keys, int n) {
  int i = blockIdx.x * 256 + threadIdx.x;
  if (i >= n) return;
  int4 c = ((const int4*)coords)[i];
  int key = (c.x * BASE + c.y + 1) * BASE2 + (c.z + 1) * BASE + (c.w + 1);
  keys[i] = key;
  table[key] = i;   // keys are unique (coords sampled without replacement)
}

// ---------------------------------------------------------------- peak detect
__global__ void k_peak(const float* __restrict__ scores, const int* __restrict__ keys,
                       const int* __restrict__ table, uint2* __restrict__ cand,
                       int* __restrict__ cand_cnt, int n) {
  int i = blockIdx.x * 256 + threadIdx.x;
  if (i >= n) return;
  float s = scores[i];
  if (!(s > TAUF)) return;
  int key = keys[i];
  const int dk[7] = {-BASE2, -BASE, -1, 0, 1, BASE, BASE2};
  float nm = NEGF;
#pragma unroll
  for (int o = 0; o < 7; ++o) {
    int j = table[key + dk[o]];
    if (j >= 0) {
      float sj = scores[j];
      if (sj > TAUF) nm = fmaxf(nm, sj);
    }
  }
  if (s >= nm - 1e-6f && s >= MIN_SCOREF) {
    int p = atomicAdd(cand_cnt, 1);
    if (p < n) cand[p] = make_uint2(__float_as_uint(s), (unsigned)i);
  }
}

// ------------------------------------------------- top-K select (one block)
// radix-select on float bits (all candidate scores in [0.5,1]) then bitonic
// sort of the boundary set; key packs (score_bits<<32)|~idx to match
// lax.top_k's stable tie-break (lower index first on equal score).
__global__ void k_select(const uint2* __restrict__ cand, const int* __restrict__ cand_cnt,
                         float* __restrict__ conf_out, int* __restrict__ owner_init,
                         int* __restrict__ peak_vox) {
  __shared__ int hist[2048];
  __shared__ unsigned long long keys_s[NS];
  __shared__ int bstar_s, m_s;
  int t = threadIdx.x;
  int nc = *cand_cnt;
  for (int b = t; b < 2048; b += 1024) hist[b] = 0;
  if (t == 0) m_s = 0;
  __syncthreads();
  for (int idx = t; idx < nc; idx += 1024) {
    unsigned sb = cand[idx].x;
    int b = (int)((sb - 0x3F000000u) >> 12);
    b = min(max(b, 0), 2047);
    atomicAdd(&hist[b], 1);
  }
  __syncthreads();
  if (t == 0) {
    int target = min(nc, KTOP);
    int run = 0, bs = 0;
    for (int b = 2047; b >= 0; --b) {
      run += hist[b];
      if (run >= target) { bs = b; break; }
    }
    bstar_s = bs;
  }
  __syncthreads();
  int bs = bstar_s;
  for (int idx = t; idx < nc; idx += 1024) {
    uint2 cv = cand[idx];
    int b = (int)((cv.x - 0x3F000000u) >> 12);
    b = min(max(b, 0), 2047);
    if (b >= bs) {
      int p = atomicAdd(&m_s, 1);
      if (p < CAP2)
        keys_s[p] = ((unsigned long long)cv.x << 32) | (unsigned)(~cv.y);
    }
  }
  __syncthreads();
  int m = min(m_s, CAP2);
  for (int idx = t; idx < NS; idx += 1024)
    if (idx >= m) keys_s[idx] = 0ULL;
  __syncthreads();
  // bitonic sort, descending
  for (int k2 = 2; k2 <= NS; k2 <<= 1) {
    for (int j2 = k2 >> 1; j2 > 0; j2 >>= 1) {
      for (int i = t; i < NS; i += 1024) {
        int ixj = i ^ j2;
        if (ixj > i) {
          unsigned long long a = keys_s[i], b = keys_s[ixj];
          bool descSeg = ((i & k2) == 0);
          bool sw = descSeg ? (a < b) : (a > b);
          if (sw) { keys_s[i] = b; keys_s[ixj] = a; }
        }
      }
      __syncthreads();
    }
  }
  if (t < KTOP) {
    int navail = min(nc, KTOP);
    if (t < navail) {
      unsigned long long kk = keys_s[t];
      float sc = __uint_as_float((unsigned)(kk >> 32));
      int vi = (int)(~(unsigned)(kk & 0xFFFFFFFFu));
      conf_out[t] = sc;
      owner_init[vi] = t;
      peak_vox[t] = vi;
    } else {
      conf_out[t] = 0.0f;
      peak_vox[t] = -1;
    }
  }
}

// ------------------------------------- owner assignment + segment sums
// Only voxels in the 7-stencil of a winning peak can be valid; visit those
// (<=1792), compute their owner exactly as the reference (max owner_init over
// their own 7-neighborhood), dedup via atomicCAS.
__global__ void k_owner(const float* __restrict__ scores, const int* __restrict__ keys,
                        const int* __restrict__ table, const int* __restrict__ owner_init,
                        const int* __restrict__ peak_vox, int* __restrict__ visited,
                        const float* __restrict__ feats, float* __restrict__ sums,
                        float* __restrict__ counts) {
  int t = blockIdx.x * blockDim.x + threadIdx.x;
  if (t >= KTOP * 7) return;
  int p = t / 7, o = t % 7;
  int v0 = peak_vox[p];
  if (v0 < 0) return;
  const int dk[7] = {-BASE2, -BASE, -1, 0, 1, BASE, BASE2};
  int v = table[keys[v0] + dk[o]];
  if (v < 0) return;
  if (!(scores[v] > TAUF)) return;            // mask[v]
  int kv = keys[v];
  int own = -1;
#pragma unroll
  for (int oo = 0; oo < 7; ++oo) {
    int j = table[kv + dk[oo]];
    if (j >= 0 && scores[j] > TAUF) own = max(own, owner_init[j]);
  }
  if (own < 0) return;
  if (atomicCAS(&visited[v], 0, 1) == 0) {
    atomicAdd(&counts[own], 1.0f);
    const float* fv = feats + (size_t)v * 128;
    float* so = sums + own * 128;
    for (int d = 0; d < 128; ++d) atomicAdd(&so[d], fv[d]);
  }
}

// ----------------------------- cols^T (32 x 257): col 0 = bg, col 1+p = conf*(mean@Wc+bc)
__global__ void k_cols(const float* __restrict__ sums, const float* __restrict__ counts,
                       const float* __restrict__ conf, const float* __restrict__ Wc,
                       const float* __restrict__ bc, const float* __restrict__ bg,
                       float* __restrict__ colsT) {
  int gid = blockIdx.x * blockDim.x + threadIdx.x;
  if (gid >= 32 * 257) return;
  int kd = gid / 257, jo = gid % 257;
  float val;
  if (jo == 0) {
    val = bg[kd];
  } else {
    int p = jo - 1;
    float inv = 1.0f / fmaxf(counts[p], 1.0f);
    float acc = bc[kd];
    const float* sp = sums + p * 128;
    for (int c = 0; c < 128; ++c) acc += sp[c] * inv * Wc[c * 32 + kd];
    val = conf[p] * acc;
  }
  colsT[kd * 257 + jo] = val;
}

// ----------------------------- phase A: desc = feats @ Wv + bv   (N x 32)
__global__ __launch_bounds__(256) void k_desc(const float* __restrict__ feats,
                                              const float* __restrict__ Wv,
                                              const float* __restrict__ bv,
                                              float* __restrict__ desc, int n) {
  __shared__ __align__(16) float Wv_s[128 * 32];
  __shared__ float feats_s[64 * 129];   // pad 129: conflict-free scalar reads
  __shared__ float bv_s[32];
  int t = threadIdx.x;
  int rbase = blockIdx.x * 64;
  {
    const float4* src = (const float4*)Wv;
    float4* dst = (float4*)Wv_s;
    for (int i = t; i < 1024; i += 256) dst[i] = src[i];
  }
  if (t < 32) bv_s[t] = bv[t];
  for (int it = 0; it < 8; ++it) {
    int idx = t + it * 256;
    int r = idx >> 5, c4 = idx & 31;
    int row = rbase + r;
    float4 v = make_float4(0.f, 0.f, 0.f, 0.f);
    if (row < n) v = *(const float4*)(feats + (size_t)row * 128 + c4 * 4);
    float* fd = &feats_s[r * 129 + c4 * 4];
    fd[0] = v.x; fd[1] = v.y; fd[2] = v.z; fd[3] = v.w;
  }
  __syncthreads();
  int r = t & 63;
  int k0 = (t >> 6) * 8;
  float acc[8];
#pragma unroll
  for (int q = 0; q < 8; ++q) acc[q] = bv_s[k0 + q];
  const float* fr = &feats_s[r * 129];
#pragma unroll 8
  for (int c = 0; c < 128; ++c) {
    float f = fr[c];
    float4 w0 = *(const float4*)&Wv_s[c * 32 + k0];
    float4 w1 = *(const float4*)&Wv_s[c * 32 + k0 + 4];
    acc[0] += f * w0.x; acc[1] += f * w0.y; acc[2] += f * w0.z; acc[3] += f * w0.w;
    acc[4] += f * w1.x; acc[5] += f * w1.y; acc[6] += f * w1.z; acc[7] += f * w1.w;
  }
  int row = rbase + r;
  if (row < n) {
    float4* dp = (float4*)(desc + (size_t)row * 32 + k0);
    dp[0] = make_float4(acc[0], acc[1], acc[2], acc[3]);
    dp[1] = make_float4(acc[4], acc[5], acc[6], acc[7]);
  }
}

// ----------------------------- phase B: out = desc @ colsT  (N x 257)
// 192 rows/block; thread tile 6 rows x 8 cols; cols_s b128 reads dense/2-way,
// desc_s scalar reads 2-way (free).
__global__ __launch_bounds__(256) void k_out(const float* __restrict__ desc,
                                             const float* __restrict__ colsT,
                                             float* __restrict__ out, int n) {
  __shared__ __align__(16) float cols_s[32 * 260];
  __shared__ float desc_s[192 * 33];
  int t = threadIdx.x;
  int rbase = blockIdx.x * 192;
  for (int idx = t; idx < 32 * 257; idx += 256) {
    int kd = idx / 257, jo = idx % 257;
    cols_s[kd * 260 + jo] = colsT[idx];
  }
  for (int it = 0; it < 6; ++it) {
    int idx = t + it * 256;
    int r = idx >> 3, c4 = idx & 7;
    int row = rbase + r;
    float4 v = make_float4(0.f, 0.f, 0.f, 0.f);
    if (row < n) v = *(const float4*)(desc + (size_t)row * 32 + c4 * 4);
    float* dd = &desc_s[r * 33 + c4 * 4];
    dd[0] = v.x; dd[1] = v.y; dd[2] = v.z; dd[3] = v.w;
  }
  __syncthreads();
  int jg = t & 7, rg = t >> 3;
  int r0 = rg * 6;
  for (int jc = 0; jc < 4; ++jc) {
    int j0 = jc * 64 + jg * 8;
    float acc[6][8];
#pragma unroll
    for (int a = 0; a < 6; ++a)
#pragma unroll
      for (int b = 0; b < 8; ++b) acc[a][b] = 0.f;
#pragma unroll 4
    for (int k = 0; k < 32; ++k) {
      float4 c0 = *(const float4*)&cols_s[k * 260 + j0];
      float4 c1 = *(const float4*)&cols_s[k * 260 + j0 + 4];
      float cj[8] = {c0.x, c0.y, c0.z, c0.w, c1.x, c1.y, c1.z, c1.w};
#pragma unroll
      for (int rr = 0; rr < 6; ++rr) {
        float f = desc_s[(r0 + rr) * 33 + k];
#pragma unroll
        for (int jj = 0; jj < 8; ++jj) acc[rr][jj] += f * cj[jj];
      }
    }
#pragma unroll
    for (int rr = 0; rr < 6; ++rr) {
      int row = rbase + r0 + rr;
      if (row < n) {
        float* op = out + 256 + (size_t)row * 257 + j0;
#pragma unroll
        for (int jj = 0; jj < 8; ++jj) op[jj] = acc[rr][jj];
      }
    }
  }
  // tail column jo = 256
  if (t < 192) {
    float accT = 0.f;
#pragma unroll 8
    for (int k = 0; k < 32; ++k) accT += desc_s[t * 33 + k] * cols_s[k * 260 + 256];
    int row = rbase + t;
    if (row < n) out[256 + (size_t)row * 257 + 256] = accT;
  }
}

// ----------------------------- fallback if ws too small for desc buffer:
// fuse: out = feats @ (Wv@colsT) + bv@colsT   (exact same math, K=128)
__global__ void k_M(const float* __restrict__ Wv, const float* __restrict__ bv,
                    const float* __restrict__ colsT, float* __restrict__ M) {
  int gid = blockIdx.x * 256 + threadIdx.x;
  if (gid >= 129 * 257) return;
  int c = gid / 257, jo = gid % 257;
  const float* wrow = (c < 128) ? (Wv + c * 32) : bv;
  float acc = 0.f;
  for (int k = 0; k < 32; ++k) acc += wrow[k] * colsT[k * 257 + jo];
  M[gid] = acc;
}
__global__ void k_fused(const float* __restrict__ feats, const float* __restrict__ M,
                        float* __restrict__ out, int n) {
  long long gid = (long long)blockIdx.x * 256 + threadIdx.x;
  if (gid >= (long long)n * 257) return;
  int i = (int)(gid / 257), jo = (int)(gid % 257);
  const float* fr = feats + (size_t)i * 128;
  float acc = M[128 * 257 + jo];
  for (int c = 0; c < 128; ++c) acc += fr[c] * M[c * 257 + jo];
  out[256 + gid] = acc;
}

// ---------------------------------------------------------------------------
extern "C" void kernel_launch(void* const* d_in, const int* in_sizes, int n_in,
                              void* d_out, int out_size, void* d_ws, size_t ws_size,
                              hipStream_t stream) {
  const int*   coords = (const int*)d_in[0];
  const float* feats  = (const float*)d_in[1];
  const float* scores = (const float*)d_in[2];
  const float* Wv     = (const float*)d_in[3];
  const float* bv     = (const float*)d_in[4];
  const float* Wc     = (const float*)d_in[5];
  const float* bc     = (const float*)d_in[6];
  const float* bg     = (const float*)d_in[7];
  float* out = (float*)d_out;
  int n = in_sizes[0] / 4;

  char* ws = (char*)d_ws;
  size_t off = 0;
  auto alloc = [&](size_t bytes) -> char* {
    char* p = ws + off;
    off = (off + bytes + 255) & ~(size_t)255;
    return p;
  };
  int*   table      = (int*)alloc((size_t)TABLE_N * 4);
  int*   keys       = (int*)alloc((size_t)n * 4);
  int*   owner_init = (int*)alloc((size_t)n * 4);
  char*  zero_base  = ws + off;                  // contiguous zero-init region
  int*   visited    = (int*)alloc((size_t)n * 4);
  int*   cand_cnt   = (int*)alloc(256);
  float* sums       = (float*)alloc(256 * 128 * 4);
  float* counts     = (float*)alloc(256 * 4);
  size_t zero_bytes = (size_t)((ws + off) - zero_base);
  uint2* cand       = (uint2*)alloc((size_t)n * 8);
  int*   peak_vox   = (int*)alloc(KTOP * 4);
  float* colsT      = (float*)alloc(32 * 257 * 4);
  size_t off_common = off;
  float* desc       = (float*)alloc((size_t)n * 32 * 4);
  bool use_split = (off <= ws_size);

  hipMemsetAsync(table, 0xFF, (size_t)TABLE_N * 4, stream);
  hipMemsetAsync(owner_init, 0xFF, (size_t)n * 4, stream);
  hipMemsetAsync(zero_base, 0, zero_bytes, stream);

  int nb = (n + 255) / 256;
  k_build<<<nb, 256, 0, stream>>>(coords, table, keys, n);
  k_peak<<<nb, 256, 0, stream>>>(scores, keys, table, cand, cand_cnt, n);
  k_select<<<1, 1024, 0, stream>>>(cand, cand_cnt, out, owner_init, peak_vox);
  k_owner<<<7, 256, 0, stream>>>(scores, keys, table, owner_init, peak_vox,
                                 visited, feats, sums, counts);
  k_cols<<<(32 * 257 + 255) / 256, 256, 0, stream>>>(sums, counts, out, Wc, bc, bg, colsT);

  if (use_split) {
    k_desc<<<(n + 63) / 64, 256, 0, stream>>>(feats, Wv, bv, desc, n);
    k_out<<<(n + 191) / 192, 256, 0, stream>>>(desc, colsT, out, n);
  } else {
    // fallback path: tiny M matrix instead of the N x 32 desc buffer
    off = off_common;
    float* M = (float*)alloc(129 * 257 * 4);
    k_M<<<(129 * 257 + 255) / 256, 256, 0, stream>>>(Wv, bv, colsT, M);
    long long total = (long long)n * 257;
    int nbf = (int)((total + 255) / 256);
    k_fused<<<nbf, 256, 0, stream>>>(feats, M, out, n);
  }
}